// Round 14
// baseline (227.628 us; speedup 1.0000x reference)
//
#include <hip/hip_runtime.h>
#include <hip/hip_bf16.h>
#include <cstdint>
#include <cstddef>

using bf16 = __hip_bfloat16;
typedef __attribute__((ext_vector_type(8))) short short8;
typedef __attribute__((ext_vector_type(4))) float f32x4;
typedef __attribute__((ext_vector_type(16))) float f32x16;

#define T_SEQ 2048
#define NHEAD 16
#define NKV 4
#define HD 128
#define CE 2048

__device__ __forceinline__ void gl_lds16(const void* g, void* l) {
  __builtin_amdgcn_global_load_lds(
      (const __attribute__((address_space(1))) unsigned int*)g,
      (__attribute__((address_space(3))) unsigned int*)l, 16, 0, 0);
}

__device__ __forceinline__ unsigned int cvtpk_bf16(float lo, float hi) {
  unsigned int r;
  asm("v_cvt_pk_bf16_f32 %0, %1, %2" : "=v"(r) : "v"(lo), "v"(hi));
  return r;
}

__device__ __forceinline__ void plswap(unsigned int& x, unsigned int& y, int hi) {
#if __has_builtin(__builtin_amdgcn_permlane32_swap)
  auto r = __builtin_amdgcn_permlane32_swap(x, y, false, false);
  x = r[0];
  y = r[1];
#else
  unsigned int xp = (unsigned int)__shfl_xor((int)x, 32);
  unsigned int yp = (unsigned int)__shfl_xor((int)y, 32);
  unsigned int nx = hi ? yp : x;
  unsigned int ny = hi ? y : xp;
  x = nx;
  y = ny;
#endif
}

// ---------------- fused prep: x->bf16 (blocks 0..8191) + 4 weight transposes ----------
__global__ void __launch_bounds__(256) prep(const float* __restrict__ x,
                                            const float* __restrict__ wq,
                                            const float* __restrict__ wk,
                                            const float* __restrict__ wv,
                                            const float* __restrict__ wc,
                                            bf16* __restrict__ xb,
                                            bf16* __restrict__ wqkvt,
                                            bf16* __restrict__ wct) {
  __shared__ float tile[32][33];
  const int tid = threadIdx.x;
  int bb = blockIdx.x;
  if (bb < 8192) {
    const int i = bb * 256 + tid;
    const float4 v = ((const float4*)x)[i];
    bf16 b0 = __float2bfloat16(v.x), b1 = __float2bfloat16(v.y),
         b2 = __float2bfloat16(v.z), b3 = __float2bfloat16(v.w);
    ushort4 u;
    u.x = *(const unsigned short*)&b0; u.y = *(const unsigned short*)&b1;
    u.z = *(const unsigned short*)&b2; u.w = *(const unsigned short*)&b3;
    ((ushort4*)xb)[i] = u;
    return;
  }
  bb -= 8192;
  const float* W;
  bf16* Wt;
  int N, bx, by;
  if (bb < 4096) {
    W = wq; Wt = wqkvt; N = 2048; bx = bb & 63; by = bb >> 6;
  } else if (bb < 5120) {
    const int c = bb - 4096;
    W = wk; Wt = wqkvt + (size_t)2048 * 2048; N = 512; bx = c & 15; by = c >> 4;
  } else if (bb < 6144) {
    const int c = bb - 5120;
    W = wv; Wt = wqkvt + (size_t)2560 * 2048; N = 512; bx = c & 15; by = c >> 4;
  } else {
    const int c = bb - 6144;
    W = wc; Wt = wct; N = 2048; bx = c & 63; by = c >> 6;
  }
  const int tx = tid & 31, ty = tid >> 5;  // 32 x 8
#pragma unroll
  for (int i = 0; i < 4; i++) {
    const int r = by * 32 + ty + i * 8;
    tile[ty + i * 8][tx] = W[(size_t)r * N + bx * 32 + tx];
  }
  __syncthreads();
#pragma unroll
  for (int i = 0; i < 4; i++) {
    const int n = bx * 32 + ty + i * 8;
    Wt[(size_t)n * 2048 + by * 32 + tx] = __float2bfloat16(tile[tx][ty + i * 8]);
  }
}

// ---------------- m201-derived 8-phase/2-K-tile GEMM ----------------
// KSPLIT: grid = 2 x (M/BM)x(N/BN); kh = wg>>log2(tiles) selects K-half; each
// block runs K/2 (NT halved, schedule identical) and writes bf16 partial at
// Cv + kh*M*N. Gate invariant unchanged (per-tile load counts identical).
template <int BM, int BN, int WM, int WN, bool OBF, bool KSPLIT = false>
__global__ void __launch_bounds__(512, 2)
gemm8i(const bf16* __restrict__ A, const bf16* __restrict__ Bt,
       void* __restrict__ Cv, int M, int N, int K) {
  constexpr int AWS = BM / 2 / WM;
  constexpr int BWS = BN / 2 / WN;
  constexpr int MH = AWS / 16;
  constexpr int NH = BWS / 16;
  constexpr int AH = BM / 128;
  constexpr int BH = BN / 128;
  constexpr int G = 2 * AH + BH;
  __shared__ bf16 smA[2][BM * 64];
  __shared__ bf16 smB[2][BN * 64];

  const int tid = threadIdx.x, lane = tid & 63, wid = tid >> 6;
  const int l15 = lane & 15, l4 = lane >> 4;
  const int wr = wid / WN, wc = wid % WN;

  const int nwg = gridDim.x;
  const int q = nwg >> 3, r = nwg & 7;
  const int xcd = blockIdx.x & 7, lin = blockIdx.x >> 3;
  const int wg = (xcd < r ? xcd * (q + 1) : r * (q + 1) + (xcd - r) * q) + lin;
  const int ntile = KSPLIT ? (nwg >> 1) : nwg;
  const int kh = KSPLIT ? (wg / ntile) : 0;
  const int tw = KSPLIT ? (wg % ntile) : wg;
  const int gw = N / BN;
  const int by = tw / gw, bx = tw % gw;
  const int row0 = by * BM, col0 = bx * BN;
  const int KT = KSPLIT ? (K >> 1) : K;
  const int kbase = kh * KT;
  const int NT = KT >> 6;
  const int NI = NT >> 1;

  const bf16* Ag = A + (size_t)row0 * K + kbase;
  const bf16* Bg = Bt + (size_t)col0 * K + kbase;

  auto stA = [&](int t, int h, int pb) {
    const int k0 = t << 6;
#pragma unroll
    for (int j = 0; j < AH; j++) {
      const int c = (h * AH + j) * 512 + tid;
      const int rowi = c >> 3;
      gl_lds16(Ag + (size_t)rowi * K + k0 + (((c & 7) ^ (rowi & 7)) << 3),
               (void*)(&smA[pb][(size_t)c << 3]));
    }
  };
  auto stB = [&](int t, int h, int pb) {
    const int k0 = t << 6;
#pragma unroll
    for (int j = 0; j < BH; j++) {
      const int c = (h * BH + j) * 512 + tid;
      const int rowi = c >> 3;
      gl_lds16(Bg + (size_t)rowi * K + k0 + (((c & 7) ^ (rowi & 7)) << 3),
               (void*)(&smB[pb][(size_t)c << 3]));
    }
  };
  auto rdA = [&](const bf16* sA, int mh, short8 (&dst)[MH][2]) {
#pragma unroll
    for (int i = 0; i < MH; i++) {
      const int rowl = mh * (BM / 2) + wr * AWS + i * 16 + l15;
#pragma unroll
      for (int kk = 0; kk < 2; kk++)
        dst[i][kk] = *(const short8*)(sA + rowl * 64 +
                                      ((((kk << 2) | l4) ^ (rowl & 7)) << 3));
    }
  };
  auto rdB = [&](const bf16* sB, int nh, short8 (&dst)[NH][2]) {
#pragma unroll
    for (int j = 0; j < NH; j++) {
      const int rowl = nh * (BN / 2) + wc * BWS + j * 16 + l15;
#pragma unroll
      for (int kk = 0; kk < 2; kk++)
        dst[j][kk] = *(const short8*)(sB + rowl * 64 +
                                      ((((kk << 2) | l4) ^ (rowl & 7)) << 3));
    }
  };

  f32x4 acc[2][2][MH][NH];
#pragma unroll
  for (int mh = 0; mh < 2; mh++)
#pragma unroll
    for (int nh = 0; nh < 2; nh++)
#pragma unroll
      for (int i = 0; i < MH; i++)
#pragma unroll
        for (int j = 0; j < NH; j++) acc[mh][nh][i][j] = (f32x4){0.f, 0.f, 0.f, 0.f};

  auto mmq = [&](short8 (&a)[MH][2], short8 (&b)[NH][2], f32x4 (&ac)[MH][NH]) {
    __builtin_amdgcn_s_setprio(1);
#pragma unroll
    for (int i = 0; i < MH; i++)
#pragma unroll
      for (int j = 0; j < NH; j++)
#pragma unroll
        for (int kk = 0; kk < 2; kk++)
          ac[i][j] = __builtin_amdgcn_mfma_f32_16x16x32_bf16(a[i][kk], b[j][kk],
                                                             ac[i][j], 0, 0, 0);
    __builtin_amdgcn_s_setprio(0);
  };

  short8 a0[MH][2], a1[MH][2], b0[NH][2], b1[NH][2];

#define LGKM0_SB                                            \
  asm volatile("s_waitcnt lgkmcnt(0)" ::: "memory");        \
  __builtin_amdgcn_sched_barrier(0);
#define GATE_G                                              \
  asm volatile("s_waitcnt vmcnt(%0)" ::"i"(G) : "memory");

  stA(0, 0, 0); stB(0, 0, 0); stA(0, 1, 0); stB(0, 1, 0);
  stA(1, 0, 1); stB(1, 0, 1); stA(1, 1, 1);
  GATE_G
  __builtin_amdgcn_s_barrier();

  for (int i = 0; i < NI - 1; ++i) {
    const int u = 2 * i, v = u + 1;
    stB(v, 1, 1);
    rdA(smA[0], 0, a0); rdB(smB[0], 0, b0);
    __builtin_amdgcn_s_barrier();
    LGKM0_SB
    mmq(a0, b0, acc[0][0]);
    __builtin_amdgcn_s_barrier();
    stA(u + 2, 0, 0);
    rdA(smA[0], 1, a1);
    __builtin_amdgcn_s_barrier();
    LGKM0_SB
    mmq(a1, b0, acc[1][0]);
    __builtin_amdgcn_s_barrier();
    stB(u + 2, 0, 0);
    rdB(smB[0], 1, b1);
    __builtin_amdgcn_s_barrier();
    LGKM0_SB
    mmq(a1, b1, acc[1][1]);
    __builtin_amdgcn_s_barrier();
    stA(u + 2, 1, 0);
    mmq(a0, b1, acc[0][1]);
    GATE_G
    __builtin_amdgcn_s_barrier();
    stB(u + 2, 1, 0);
    rdA(smA[1], 0, a0); rdB(smB[1], 0, b0);
    __builtin_amdgcn_s_barrier();
    LGKM0_SB
    mmq(a0, b0, acc[0][0]);
    __builtin_amdgcn_s_barrier();
    stA(v + 2, 0, 1);
    rdA(smA[1], 1, a1);
    __builtin_amdgcn_s_barrier();
    LGKM0_SB
    mmq(a1, b0, acc[1][0]);
    __builtin_amdgcn_s_barrier();
    stB(v + 2, 0, 1);
    rdB(smB[1], 1, b1);
    __builtin_amdgcn_s_barrier();
    LGKM0_SB
    mmq(a1, b1, acc[1][1]);
    __builtin_amdgcn_s_barrier();
    stA(v + 2, 1, 1);
    mmq(a0, b1, acc[0][1]);
    GATE_G
    __builtin_amdgcn_s_barrier();
  }

  {
    stB(NT - 1, 1, 1);
    rdA(smA[0], 0, a0); rdB(smB[0], 0, b0);
    __builtin_amdgcn_s_barrier();
    LGKM0_SB
    mmq(a0, b0, acc[0][0]);
    __builtin_amdgcn_s_barrier();
    rdA(smA[0], 1, a1);
    __builtin_amdgcn_s_barrier();
    LGKM0_SB
    mmq(a1, b0, acc[1][0]);
    __builtin_amdgcn_s_barrier();
    rdB(smB[0], 1, b1);
    __builtin_amdgcn_s_barrier();
    LGKM0_SB
    mmq(a1, b1, acc[1][1]);
    __builtin_amdgcn_s_barrier();
    mmq(a0, b1, acc[0][1]);
    asm volatile("s_waitcnt vmcnt(0)" ::: "memory");
    __builtin_amdgcn_s_barrier();
    rdA(smA[1], 0, a0); rdB(smB[1], 0, b0);
    __builtin_amdgcn_s_barrier();
    LGKM0_SB
    mmq(a0, b0, acc[0][0]);
    __builtin_amdgcn_s_barrier();
    rdA(smA[1], 1, a1);
    __builtin_amdgcn_s_barrier();
    LGKM0_SB
    mmq(a1, b0, acc[1][0]);
    __builtin_amdgcn_s_barrier();
    rdB(smB[1], 1, b1);
    __builtin_amdgcn_s_barrier();
    LGKM0_SB
    mmq(a1, b1, acc[1][1]);
    mmq(a0, b1, acc[0][1]);
  }

#pragma unroll
  for (int mh = 0; mh < 2; mh++)
#pragma unroll
    for (int nh = 0; nh < 2; nh++)
#pragma unroll
      for (int i = 0; i < MH; i++)
#pragma unroll
        for (int j = 0; j < NH; j++)
#pragma unroll
          for (int rr = 0; rr < 4; rr++) {
            const size_t row = row0 + mh * (BM / 2) + wr * AWS + i * 16 + l4 * 4 + rr;
            const size_t col = col0 + nh * (BN / 2) + wc * BWS + j * 16 + l15;
            if constexpr (KSPLIT)
              ((bf16*)Cv)[(size_t)kh * M * N + row * N + col] =
                  __float2bfloat16(acc[mh][nh][i][j][rr]);
            else if constexpr (OBF)
              ((bf16*)Cv)[row * N + col] = __float2bfloat16(acc[mh][nh][i][j][rr]);
            else
              ((float*)Cv)[row * N + col] = acc[mh][nh][i][j][rr];
          }
#undef LGKM0_SB
#undef GATE_G
}

// ---------------- sum two bf16 split-K partials -> f32 out ----------------
__global__ void __launch_bounds__(256) proj_combine(const bf16* __restrict__ P,
                                                    float* __restrict__ out) {
  const size_t i = ((size_t)blockIdx.x * 256 + threadIdx.x) * 8;
  const short8 v0 = *(const short8*)(P + i);
  const short8 v1 = *(const short8*)(P + 8388608 + i);
  float o[8];
#pragma unroll
  for (int j = 0; j < 8; j++) {
    const unsigned short u0 = (unsigned short)v0[j], u1 = (unsigned short)v1[j];
    o[j] = __bfloat162float(*(const bf16*)&u0) + __bfloat162float(*(const bf16*)&u1);
  }
  *(float4*)(out + i) = (float4){o[0], o[1], o[2], o[3]};
  *(float4*)(out + i + 4) = (float4){o[4], o[5], o[6], o[7]};
}

// ---------------- RMSNorm + RoPE + layout (bf16 input) ----------------
__global__ void __launch_bounds__(256) qkv_post(const bf16* __restrict__ QKV,
                                                const float* __restrict__ qw,
                                                const float* __restrict__ kw,
                                                bf16* __restrict__ Qo,
                                                bf16* __restrict__ Ko,
                                                bf16* __restrict__ Vto) {
  const int g = blockIdx.x * 4 + (threadIdx.x >> 6);
  const int lane = threadIdx.x & 63;
  const int hh = g % 24;
  const int bt = g / 24;
  const int b = bt >> 11, t = bt & (T_SEQ - 1);
  int off;
  if (hh < 16) off = hh * 128;
  else if (hh < 20) off = 2048 + (hh - 16) * 128;
  else off = 2560 + (hh - 20) * 128;
  const ushort2 xr = *(const ushort2*)(QKV + (size_t)bt * 3072 + off + lane * 2);
  const float xx = __bfloat162float(*(const bf16*)&xr.x);
  const float xy = __bfloat162float(*(const bf16*)&xr.y);
  if (hh < 20) {
    float ss = xx * xx + xy * xy;
    ss += __shfl_xor(ss, 1);  ss += __shfl_xor(ss, 2);  ss += __shfl_xor(ss, 4);
    ss += __shfl_xor(ss, 8);  ss += __shfl_xor(ss, 16); ss += __shfl_xor(ss, 32);
    const float rms = rsqrtf(ss * (1.0f / 128.0f) + 1e-5f);
    const float* w = (hh < 16) ? qw : kw;
    const float x0 = xx * rms * w[lane * 2];
    const float x1 = xy * rms * w[lane * 2 + 1];
    const float inv = exp2f((float)lane * (-13.287712379549449f / 64.0f));
    const float th = (float)t * inv;
    const float sn = sinf(th), cs = cosf(th);
    const float y0 = x0 * cs - x1 * sn;
    const float y1 = x0 * sn + x1 * cs;
    const bf16 o0 = __float2bfloat16(y0), o1 = __float2bfloat16(y1);
    if (hh < 16) {
      bf16* d = Qo + ((size_t)(b * NHEAD + hh) * T_SEQ + t) * HD + lane * 2;
      d[0] = o0; d[1] = o1;
    } else {
      bf16* d = Ko + ((size_t)(b * NKV + (hh - 16)) * T_SEQ + t) * HD + lane * 2;
      d[0] = o0; d[1] = o1;
    }
  } else {
    bf16* d = Vto + ((size_t)(b * NKV + (hh - 20)) * HD + lane * 2) * T_SEQ + t;
    d[0] = __float2bfloat16(xx);
    d[T_SEQ] = __float2bfloat16(xy);
  }
}

// ---------------- GQA causal flash attention: R6 inner loop + flash-split ----------
__constant__ unsigned short JT[30] = {
    0x0605, 0x160A, 0x160B, 0x266B, 0x160F,                          // len 6
    0x0504, 0x1508, 0x1509, 0x2559, 0x256A, 0x150C, 0x150D, 0x255D,  // len 5
    0x150E, 0x255E, 0x35AE, 0x256F, 0x35BF,                          // len 5
    0x0403, 0x1406, 0x1407, 0x2447, 0x2458, 0x245C, 0x349C, 0x34AD,  // len 4
    0x0302, 0x2346,                                                  // len 3
    0x0201, 0x0100};                                                 // len 2,1

#define ATTN_CL 0.12754125f  // (1/sqrt(128)) * log2(e)

__global__ void __launch_bounds__(256, 2) attn_fwd(const bf16* __restrict__ Q,
                                                   const bf16* __restrict__ K,
                                                   const bf16* __restrict__ Vt,
                                                   bf16* __restrict__ Y,
                                                   bf16* __restrict__ PO,
                                                   float* __restrict__ PML) {
  __shared__ bf16 smK[128 * 128];
  __shared__ bf16 smV[128 * 128];

  const int bid = blockIdx.x;
  const int bh = bid & 31;
  const int jobi = bid >> 5;       // 0..29, LPT order
  const unsigned int e = JT[jobi];
  const int jq = e & 15;
  const int lo = (e >> 4) & 15;
  const int len = (e >> 8) & 15;
  const int part = e >> 12;
  const int hi_t = lo + len;

  const int h = bh & (NHEAD - 1), b = bh >> 4;
  const int bkv = b * NKV + (h >> 2);

  const int tid = threadIdx.x, wid = tid >> 6, lane = tid & 63;
  const int l31 = lane & 31, hi = lane >> 5;
  const int q0w = jq * 128 + wid * 32;
  const int trow = tid >> 4, tslot = tid & 15;

  const bf16* Kb = K + (size_t)bkv * T_SEQ * HD;
  const bf16* Vb = Vt + (size_t)bkv * HD * T_SEQ;

  const bf16* Qrow = Q + ((size_t)bh * T_SEQ + q0w + l31) * HD + hi * 8;
  short8 qf[8];
#pragma unroll
  for (int ds = 0; ds < 8; ds++) qf[ds] = *(const short8*)(Qrow + ds * 16);

  f32x16 o[4];
#pragma unroll
  for (int d = 0; d < 4; d++) o[d] = (f32x16)(0.f);
  float mrun = -INFINITY, lrun = 0.f;

  constexpr float CL = ATTN_CL;

  for (int t = lo; t < hi_t; t++) {
    const int k0 = t * 128;
    __syncthreads();
#pragma unroll
    for (int i = 0; i < 8; i++) {
      const int row = i * 16 + trow;
      const int ss = (tslot ^ (row & 15)) * 8;
      gl_lds16(Kb + (size_t)(k0 + row) * HD + ss, (void*)((char*)smK + i * 4096 + wid * 1024));
      gl_lds16(Vb + (size_t)row * T_SEQ + k0 + ss, (void*)((char*)smV + i * 4096 + wid * 1024));
    }
    __syncthreads();

    const bool diag = (t == jq);
    const int glim = diag ? wid : 3;

    f32x16 sg[4];
#pragma unroll
    for (int g = 0; g < 4; g++) {
      if (g > glim) continue;
      f32x16 acc = (f32x16)(0.f);
#pragma unroll
      for (int ds = 0; ds < 8; ds++) {
        const int row = g * 32 + l31;
        const short8 kf = *(const short8*)(smK + (size_t)row * 128 +
                                           (((ds << 1) | hi) ^ (row & 15)) * 8);
        acc = __builtin_amdgcn_mfma_f32_32x32x16_bf16(kf, qf[ds], acc, 0, 0, 0);
      }
      sg[g] = acc;
    }
    float tmax = -INFINITY;
#pragma unroll
    for (int g = 0; g < 4; g++) {
      if (g > glim) continue;
      if (diag && g == wid) {
#pragma unroll
        for (int r = 0; r < 16; r++) {
          const int kr = (r & 3) + 8 * (r >> 2) + (hi << 2);
          if (kr > l31) sg[g][r] = -INFINITY;
        }
      }
#pragma unroll
      for (int r = 0; r < 16; r++) tmax = fmaxf(tmax, sg[g][r]);
    }
    tmax = fmaxf(tmax, __shfl_xor(tmax, 32));
    const float mnew = fmaxf(mrun, tmax);
    const float f = exp2f((mrun - mnew) * CL);
    mrun = mnew;
    lrun *= f;
#pragma unroll
    for (int d = 0; d < 4; d++)
#pragma unroll
      for (int r = 0; r < 16; r++) o[d][r] *= f;

    float lsum = 0.f;
#pragma unroll
    for (int g = 0; g < 4; g++) {
      if (g > glim) continue;
      float pp[16];
      float s0 = 0.f, s1 = 0.f;
#pragma unroll
      for (int r = 0; r < 16; r++) pp[r] = exp2f((sg[g][r] - mnew) * CL);
#pragma unroll
      for (int r = 0; r < 8; r++) { s0 += pp[2 * r]; s1 += pp[2 * r + 1]; }
      lsum += s0 + s1;

      unsigned int w0 = cvtpk_bf16(pp[0], pp[1]),  w2 = cvtpk_bf16(pp[4], pp[5]);
      unsigned int w1 = cvtpk_bf16(pp[2], pp[3]),  w3 = cvtpk_bf16(pp[6], pp[7]);
      unsigned int w4 = cvtpk_bf16(pp[8], pp[9]),  w6 = cvtpk_bf16(pp[12], pp[13]);
      unsigned int w5 = cvtpk_bf16(pp[10], pp[11]), w7 = cvtpk_bf16(pp[14], pp[15]);
      plswap(w0, w2, hi); plswap(w1, w3, hi);
      plswap(w4, w6, hi); plswap(w5, w7, hi);
      union { unsigned int u[4]; short8 s8; } pa0, pa1;
      pa0.u[0] = w0; pa0.u[1] = w1; pa0.u[2] = w2; pa0.u[3] = w3;
      pa1.u[0] = w4; pa1.u[1] = w5; pa1.u[2] = w6; pa1.u[3] = w7;

#pragma unroll
      for (int d = 0; d < 4; d++) {
        const int row = d * 32 + l31;
        const int ks0 = g * 2, ks1 = g * 2 + 1;
        const short8 vf0 = *(const short8*)(smV + (size_t)row * 128 +
                                            (((ks0 << 1) | hi) ^ (row & 15)) * 8);
        const short8 vf1 = *(const short8*)(smV + (size_t)row * 128 +
                                            (((ks1 << 1) | hi) ^ (row & 15)) * 8);
        o[d] = __builtin_amdgcn_mfma_f32_32x32x16_bf16(vf0, pa0.s8, o[d], 0, 0, 0);
        o[d] = __builtin_amdgcn_mfma_f32_32x32x16_bf16(vf1, pa1.s8, o[d], 0, 0, 0);
      }
    }
    lrun += lsum + __shfl_xor(lsum, 32);
  }

  if (part == 0) {
    const float inv = 1.0f / lrun;
    bf16* yrow = Y + ((size_t)(b * T_SEQ + q0w + l31)) * CE + h * HD;
#pragma unroll
    for (int d = 0; d < 4; d++) {
#pragma unroll
      for (int rg = 0; rg < 4; rg++) {
        ushort4 u;
        bf16 e0 = __float2bfloat16(o[d][rg * 4 + 0] * inv);
        bf16 e1 = __float2bfloat16(o[d][rg * 4 + 1] * inv);
        bf16 e2 = __float2bfloat16(o[d][rg * 4 + 2] * inv);
        bf16 e3 = __float2bfloat16(o[d][rg * 4 + 3] * inv);
        u.x = *(const unsigned short*)&e0; u.y = *(const unsigned short*)&e1;
        u.z = *(const unsigned short*)&e2; u.w = *(const unsigned short*)&e3;
        *(ushort4*)(yrow + d * 32 + rg * 8 + (hi << 2)) = u;
      }
    }
  } else {
    const int plocal = (jq < 12) ? (jq - 6) * 2 + (part - 1)
                                 : 12 + (jq - 12) * 3 + (part - 1);
    const int pidx = bh * 24 + plocal;
    bf16* po = PO + (size_t)pidx * 16384;
    const int row = wid * 32 + l31;
#pragma unroll
    for (int d = 0; d < 4; d++) {
#pragma unroll
      for (int rg = 0; rg < 4; rg++) {
        ushort4 u;
        bf16 e0 = __float2bfloat16(o[d][rg * 4 + 0]);
        bf16 e1 = __float2bfloat16(o[d][rg * 4 + 1]);
        bf16 e2 = __float2bfloat16(o[d][rg * 4 + 2]);
        bf16 e3 = __float2bfloat16(o[d][rg * 4 + 3]);
        u.x = *(const unsigned short*)&e0; u.y = *(const unsigned short*)&e1;
        u.z = *(const unsigned short*)&e2; u.w = *(const unsigned short*)&e3;
        *(ushort4*)(po + (size_t)row * 128 + d * 32 + rg * 8 + (hi << 2)) = u;
      }
    }
    if (hi == 0) {
      PML[(size_t)pidx * 256 + row * 2 + 0] = mrun;
      PML[(size_t)pidx * 256 + row * 2 + 1] = lrun;
    }
  }
}

// ---------------- combine split-KV partials (2 or 3 parts) -> final bf16 y ----------
__global__ void __launch_bounds__(256) attn_combine(const bf16* __restrict__ PO,
                                                    const float* __restrict__ PML,
                                                    bf16* __restrict__ Y) {
  const int bid = blockIdx.x;              // 32 bh x 10 J x 4 row-chunks = 1280
  const int rb = bid & 3;
  const int Jl = (bid >> 2) % 10;
  const int bh = bid / 40;
  const int J = 6 + Jl;
  const bool has2 = (J >= 12);
  const int base = bh * 24 + (has2 ? 12 + (J - 12) * 3 : (J - 6) * 2);
  const int tid = threadIdx.x;
  const int row = rb * 32 + (tid >> 3);
  const int c0 = (tid & 7) * 16;
  const int b = bh >> 4, h = bh & 15;

  const float m0 = PML[(size_t)(base + 0) * 256 + row * 2 + 0];
  const float l0 = PML[(size_t)(base + 0) * 256 + row * 2 + 1];
  const float m1 = PML[(size_t)(base + 1) * 256 + row * 2 + 0];
  const float l1 = PML[(size_t)(base + 1) * 256 + row * 2 + 1];
  float m2 = -INFINITY, l2 = 0.f;
  if (has2) {
    m2 = PML[(size_t)(base + 2) * 256 + row * 2 + 0];
    l2 = PML[(size_t)(base + 2) * 256 + row * 2 + 1];
  }
  const float mx = fmaxf(fmaxf(m0, m1), m2);
  const float w0 = exp2f((m0 - mx) * ATTN_CL);
  const float w1 = exp2f((m1 - mx) * ATTN_CL);
  const float w2 = has2 ? exp2f((m2 - mx) * ATTN_CL) : 0.f;
  const float inv = 1.0f / (w0 * l0 + w1 * l1 + w2 * l2);

  const bf16* p0 = PO + (size_t)(base + 0) * 16384 + (size_t)row * 128 + c0;
  const bf16* p1 = PO + (size_t)(base + 1) * 16384 + (size_t)row * 128 + c0;
  const bf16* p2 = PO + (size_t)(base + 2) * 16384 + (size_t)row * 128 + c0;

  float acc[16];
#pragma unroll
  for (int half = 0; half < 2; half++) {
    const short8 v0 = *(const short8*)(p0 + half * 8);
    const short8 v1 = *(const short8*)(p1 + half * 8);
#pragma unroll
    for (int i = 0; i < 8; i++) {
      const unsigned short u0 = (unsigned short)v0[i], u1 = (unsigned short)v1[i];
      acc[half * 8 + i] = w0 * __bfloat162float(*(const bf16*)&u0) +
                          w1 * __bfloat162float(*(const bf16*)&u1);
    }
  }
  if (has2) {
#pragma unroll
    for (int half = 0; half < 2; half++) {
      const short8 v2 = *(const short8*)(p2 + half * 8);
#pragma unroll
      for (int i = 0; i < 8; i++) {
        const unsigned short u2 = (unsigned short)v2[i];
        acc[half * 8 + i] += w2 * __bfloat162float(*(const bf16*)&u2);
      }
    }
  }

  bf16* yp = Y + ((size_t)(b * T_SEQ + J * 128 + row)) * CE + h * HD + c0;
#pragma unroll
  for (int half = 0; half < 2; half++) {
    short8 out;
#pragma unroll
    for (int i = 0; i < 8; i++) {
      const bf16 ev = __float2bfloat16(acc[half * 8 + i] * inv);
      out[i] = *(const short*)&ev;
    }
    *(short8*)(yp + half * 8) = out;
  }
}

// ---------------- launch ----------------
extern "C" void kernel_launch(void* const* d_in, const int* in_sizes, int n_in,
                              void* d_out, int out_size, void* d_ws, size_t ws_size,
                              hipStream_t stream) {
  const float* x   = (const float*)d_in[0];
  const float* wq  = (const float*)d_in[1];
  const float* wk  = (const float*)d_in[2];
  const float* wv  = (const float*)d_in[3];
  const float* wc  = (const float*)d_in[4];
  const float* qnw = (const float*)d_in[5];
  const float* knw = (const float*)d_in[6];
  float* out = (float*)d_out;

  char* ws = (char*)d_ws;
  bf16*  xb    = (bf16*)(ws);                    // 16 MB
  bf16*  wqkvt = (bf16*)(ws + 16777216);         // 12 MB
  bf16*  wct   = (bf16*)(ws + 29360128);         //  8 MB
  bf16*  qkv   = (bf16*)(ws + 37748736);         // 24 MB (dead after qkv_post)
  bf16*  partO = (bf16*)(ws + 37748736);         // 24 MB (overlaps dead qkv)
  float* partML= (float*)(ws + 62914560);        // 768 KB
  bf16*  projP = (bf16*)(ws + 37748736);         // 32 MB (dead after attn_combine)
  bf16*  Qb    = (bf16*)(ws + 88080384);         // 16 MB (B,H,T,D)
  bf16*  Kb    = (bf16*)(ws + 104857600);        //  4 MB (B,KVH,T,D)
  bf16*  Vtb   = (bf16*)(ws + 109051904);        //  4 MB (B,KVH,D,T)
  bf16*  yb    = (bf16*)(ws + 113246208);        // 16 MB

  prep<<<18432, 256, 0, stream>>>(x, wq, wk, wv, wc, xb, wqkvt, wct);
  gemm8i<256, 256, 2, 4, true><<<192, 512, 0, stream>>>(xb, wqkvt, qkv, 4096, 3072, 2048);
  qkv_post<<<24576, 256, 0, stream>>>(qkv, qnw, knw, Qb, Kb, Vtb);
  attn_fwd<<<960, 256, 0, stream>>>(Qb, Kb, Vtb, yb, partO, partML);
  attn_combine<<<1280, 256, 0, stream>>>(partO, partML, yb);
  gemm8i<256, 256, 2, 4, true, true><<<256, 512, 0, stream>>>(yb, wct, projP, 4096, 2048, 2048);
  proj_combine<<<4096, 256, 0, stream>>>(projP, out);
}

// Round 15
// 223.282 us; speedup vs baseline: 1.0195x; 1.0195x over previous
//
#include <hip/hip_runtime.h>
#include <hip/hip_bf16.h>
#include <cstdint>
#include <cstddef>

using bf16 = __hip_bfloat16;
typedef __attribute__((ext_vector_type(8))) short short8;
typedef __attribute__((ext_vector_type(4))) float f32x4;
typedef __attribute__((ext_vector_type(16))) float f32x16;

#define T_SEQ 2048
#define NHEAD 16
#define NKV 4
#define HD 128
#define CE 2048

__device__ __forceinline__ void gl_lds16(const void* g, void* l) {
  __builtin_amdgcn_global_load_lds(
      (const __attribute__((address_space(1))) unsigned int*)g,
      (__attribute__((address_space(3))) unsigned int*)l, 16, 0, 0);
}

__device__ __forceinline__ unsigned int cvtpk_bf16(float lo, float hi) {
  unsigned int r;
  asm("v_cvt_pk_bf16_f32 %0, %1, %2" : "=v"(r) : "v"(lo), "v"(hi));
  return r;
}

__device__ __forceinline__ void plswap(unsigned int& x, unsigned int& y, int hi) {
#if __has_builtin(__builtin_amdgcn_permlane32_swap)
  auto r = __builtin_amdgcn_permlane32_swap(x, y, false, false);
  x = r[0];
  y = r[1];
#else
  unsigned int xp = (unsigned int)__shfl_xor((int)x, 32);
  unsigned int yp = (unsigned int)__shfl_xor((int)y, 32);
  unsigned int nx = hi ? yp : x;
  unsigned int ny = hi ? y : xp;
  x = nx;
  y = ny;
#endif
}

// ---------------- fused prep: x->bf16 (blocks 0..8191) + 4 weight transposes ----------
__global__ void __launch_bounds__(256) prep(const float* __restrict__ x,
                                            const float* __restrict__ wq,
                                            const float* __restrict__ wk,
                                            const float* __restrict__ wv,
                                            const float* __restrict__ wc,
                                            bf16* __restrict__ xb,
                                            bf16* __restrict__ wqkvt,
                                            bf16* __restrict__ wct) {
  __shared__ float tile[32][33];
  const int tid = threadIdx.x;
  int bb = blockIdx.x;
  if (bb < 8192) {
    const int i = bb * 256 + tid;
    const float4 v = ((const float4*)x)[i];
    bf16 b0 = __float2bfloat16(v.x), b1 = __float2bfloat16(v.y),
         b2 = __float2bfloat16(v.z), b3 = __float2bfloat16(v.w);
    ushort4 u;
    u.x = *(const unsigned short*)&b0; u.y = *(const unsigned short*)&b1;
    u.z = *(const unsigned short*)&b2; u.w = *(const unsigned short*)&b3;
    ((ushort4*)xb)[i] = u;
    return;
  }
  bb -= 8192;
  const float* W;
  bf16* Wt;
  int N, bx, by;
  if (bb < 4096) {
    W = wq; Wt = wqkvt; N = 2048; bx = bb & 63; by = bb >> 6;
  } else if (bb < 5120) {
    const int c = bb - 4096;
    W = wk; Wt = wqkvt + (size_t)2048 * 2048; N = 512; bx = c & 15; by = c >> 4;
  } else if (bb < 6144) {
    const int c = bb - 5120;
    W = wv; Wt = wqkvt + (size_t)2560 * 2048; N = 512; bx = c & 15; by = c >> 4;
  } else {
    const int c = bb - 6144;
    W = wc; Wt = wct; N = 2048; bx = c & 63; by = c >> 6;
  }
  const int tx = tid & 31, ty = tid >> 5;  // 32 x 8
#pragma unroll
  for (int i = 0; i < 4; i++) {
    const int r = by * 32 + ty + i * 8;
    tile[ty + i * 8][tx] = W[(size_t)r * N + bx * 32 + tx];
  }
  __syncthreads();
#pragma unroll
  for (int i = 0; i < 4; i++) {
    const int n = bx * 32 + ty + i * 8;
    Wt[(size_t)n * 2048 + by * 32 + tx] = __float2bfloat16(tile[tx][ty + i * 8]);
  }
}

// ---------------- m201-derived 8-phase/2-K-tile GEMM (no XCD swizzle: L3-fit) --------
template <int BM, int BN, int WM, int WN, bool OBF>
__global__ void __launch_bounds__(512, 2)
gemm8i(const bf16* __restrict__ A, const bf16* __restrict__ Bt,
       void* __restrict__ Cv, int M, int N, int K) {
  constexpr int AWS = BM / 2 / WM;
  constexpr int BWS = BN / 2 / WN;
  constexpr int MH = AWS / 16;
  constexpr int NH = BWS / 16;
  constexpr int AH = BM / 128;
  constexpr int BH = BN / 128;
  constexpr int G = 2 * AH + BH;
  __shared__ bf16 smA[2][BM * 64];
  __shared__ bf16 smB[2][BN * 64];

  const int tid = threadIdx.x, lane = tid & 63, wid = tid >> 6;
  const int l15 = lane & 15, l4 = lane >> 4;
  const int wr = wid / WN, wc = wid % WN;

  const int wg = blockIdx.x;  // linear: working set is L3-resident (m160)
  const int gw = N / BN;
  const int by = wg / gw, bx = wg % gw;
  const int row0 = by * BM, col0 = bx * BN;
  const int NT = K >> 6;
  const int NI = NT >> 1;

  const bf16* Ag = A + (size_t)row0 * K;
  const bf16* Bg = Bt + (size_t)col0 * K;

  auto stA = [&](int t, int h, int pb) {
    const int k0 = t << 6;
#pragma unroll
    for (int j = 0; j < AH; j++) {
      const int c = (h * AH + j) * 512 + tid;
      const int rowi = c >> 3;
      gl_lds16(Ag + (size_t)rowi * K + k0 + (((c & 7) ^ (rowi & 7)) << 3),
               (void*)(&smA[pb][(size_t)c << 3]));
    }
  };
  auto stB = [&](int t, int h, int pb) {
    const int k0 = t << 6;
#pragma unroll
    for (int j = 0; j < BH; j++) {
      const int c = (h * BH + j) * 512 + tid;
      const int rowi = c >> 3;
      gl_lds16(Bg + (size_t)rowi * K + k0 + (((c & 7) ^ (rowi & 7)) << 3),
               (void*)(&smB[pb][(size_t)c << 3]));
    }
  };
  auto rdA = [&](const bf16* sA, int mh, short8 (&dst)[MH][2]) {
#pragma unroll
    for (int i = 0; i < MH; i++) {
      const int rowl = mh * (BM / 2) + wr * AWS + i * 16 + l15;
#pragma unroll
      for (int kk = 0; kk < 2; kk++)
        dst[i][kk] = *(const short8*)(sA + rowl * 64 +
                                      ((((kk << 2) | l4) ^ (rowl & 7)) << 3));
    }
  };
  auto rdB = [&](const bf16* sB, int nh, short8 (&dst)[NH][2]) {
#pragma unroll
    for (int j = 0; j < NH; j++) {
      const int rowl = nh * (BN / 2) + wc * BWS + j * 16 + l15;
#pragma unroll
      for (int kk = 0; kk < 2; kk++)
        dst[j][kk] = *(const short8*)(sB + rowl * 64 +
                                      ((((kk << 2) | l4) ^ (rowl & 7)) << 3));
    }
  };

  f32x4 acc[2][2][MH][NH];
#pragma unroll
  for (int mh = 0; mh < 2; mh++)
#pragma unroll
    for (int nh = 0; nh < 2; nh++)
#pragma unroll
      for (int i = 0; i < MH; i++)
#pragma unroll
        for (int j = 0; j < NH; j++) acc[mh][nh][i][j] = (f32x4){0.f, 0.f, 0.f, 0.f};

  auto mmq = [&](short8 (&a)[MH][2], short8 (&b)[NH][2], f32x4 (&ac)[MH][NH]) {
    __builtin_amdgcn_s_setprio(1);
#pragma unroll
    for (int i = 0; i < MH; i++)
#pragma unroll
      for (int j = 0; j < NH; j++)
#pragma unroll
        for (int kk = 0; kk < 2; kk++)
          ac[i][j] = __builtin_amdgcn_mfma_f32_16x16x32_bf16(a[i][kk], b[j][kk],
                                                             ac[i][j], 0, 0, 0);
    __builtin_amdgcn_s_setprio(0);
  };

  short8 a0[MH][2], a1[MH][2], b0[NH][2], b1[NH][2];

#define LGKM0_SB                                            \
  asm volatile("s_waitcnt lgkmcnt(0)" ::: "memory");        \
  __builtin_amdgcn_sched_barrier(0);
#define GATE_G                                              \
  asm volatile("s_waitcnt vmcnt(%0)" ::"i"(G) : "memory");

  stA(0, 0, 0); stB(0, 0, 0); stA(0, 1, 0); stB(0, 1, 0);
  stA(1, 0, 1); stB(1, 0, 1); stA(1, 1, 1);
  GATE_G
  __builtin_amdgcn_s_barrier();

  for (int i = 0; i < NI - 1; ++i) {
    const int u = 2 * i, v = u + 1;
    stB(v, 1, 1);
    rdA(smA[0], 0, a0); rdB(smB[0], 0, b0);
    __builtin_amdgcn_s_barrier();
    LGKM0_SB
    mmq(a0, b0, acc[0][0]);
    __builtin_amdgcn_s_barrier();
    stA(u + 2, 0, 0);
    rdA(smA[0], 1, a1);
    __builtin_amdgcn_s_barrier();
    LGKM0_SB
    mmq(a1, b0, acc[1][0]);
    __builtin_amdgcn_s_barrier();
    stB(u + 2, 0, 0);
    rdB(smB[0], 1, b1);
    __builtin_amdgcn_s_barrier();
    LGKM0_SB
    mmq(a1, b1, acc[1][1]);
    __builtin_amdgcn_s_barrier();
    stA(u + 2, 1, 0);
    mmq(a0, b1, acc[0][1]);
    GATE_G
    __builtin_amdgcn_s_barrier();
    stB(u + 2, 1, 0);
    rdA(smA[1], 0, a0); rdB(smB[1], 0, b0);
    __builtin_amdgcn_s_barrier();
    LGKM0_SB
    mmq(a0, b0, acc[0][0]);
    __builtin_amdgcn_s_barrier();
    stA(v + 2, 0, 1);
    rdA(smA[1], 1, a1);
    __builtin_amdgcn_s_barrier();
    LGKM0_SB
    mmq(a1, b0, acc[1][0]);
    __builtin_amdgcn_s_barrier();
    stB(v + 2, 0, 1);
    rdB(smB[1], 1, b1);
    __builtin_amdgcn_s_barrier();
    LGKM0_SB
    mmq(a1, b1, acc[1][1]);
    __builtin_amdgcn_s_barrier();
    stA(v + 2, 1, 1);
    mmq(a0, b1, acc[0][1]);
    GATE_G
    __builtin_amdgcn_s_barrier();
  }

  {
    stB(NT - 1, 1, 1);
    rdA(smA[0], 0, a0); rdB(smB[0], 0, b0);
    __builtin_amdgcn_s_barrier();
    LGKM0_SB
    mmq(a0, b0, acc[0][0]);
    __builtin_amdgcn_s_barrier();
    rdA(smA[0], 1, a1);
    __builtin_amdgcn_s_barrier();
    LGKM0_SB
    mmq(a1, b0, acc[1][0]);
    __builtin_amdgcn_s_barrier();
    rdB(smB[0], 1, b1);
    __builtin_amdgcn_s_barrier();
    LGKM0_SB
    mmq(a1, b1, acc[1][1]);
    __builtin_amdgcn_s_barrier();
    mmq(a0, b1, acc[0][1]);
    asm volatile("s_waitcnt vmcnt(0)" ::: "memory");
    __builtin_amdgcn_s_barrier();
    rdA(smA[1], 0, a0); rdB(smB[1], 0, b0);
    __builtin_amdgcn_s_barrier();
    LGKM0_SB
    mmq(a0, b0, acc[0][0]);
    __builtin_amdgcn_s_barrier();
    rdA(smA[1], 1, a1);
    __builtin_amdgcn_s_barrier();
    LGKM0_SB
    mmq(a1, b0, acc[1][0]);
    __builtin_amdgcn_s_barrier();
    rdB(smB[1], 1, b1);
    __builtin_amdgcn_s_barrier();
    LGKM0_SB
    mmq(a1, b1, acc[1][1]);
    mmq(a0, b1, acc[0][1]);
  }

#pragma unroll
  for (int mh = 0; mh < 2; mh++)
#pragma unroll
    for (int nh = 0; nh < 2; nh++)
#pragma unroll
      for (int i = 0; i < MH; i++)
#pragma unroll
        for (int j = 0; j < NH; j++)
#pragma unroll
          for (int rr = 0; rr < 4; rr++) {
            const size_t row = row0 + mh * (BM / 2) + wr * AWS + i * 16 + l4 * 4 + rr;
            const size_t col = col0 + nh * (BN / 2) + wc * BWS + j * 16 + l15;
            if constexpr (OBF)
              ((bf16*)Cv)[row * N + col] = __float2bfloat16(acc[mh][nh][i][j][rr]);
            else
              ((float*)Cv)[row * N + col] = acc[mh][nh][i][j][rr];
          }
#undef LGKM0_SB
#undef GATE_G
}

// ---------------- RMSNorm + RoPE + layout (bf16 input) ----------------
__global__ void __launch_bounds__(256) qkv_post(const bf16* __restrict__ QKV,
                                                const float* __restrict__ qw,
                                                const float* __restrict__ kw,
                                                bf16* __restrict__ Qo,
                                                bf16* __restrict__ Ko,
                                                bf16* __restrict__ Vto) {
  const int g = blockIdx.x * 4 + (threadIdx.x >> 6);
  const int lane = threadIdx.x & 63;
  const int hh = g % 24;
  const int bt = g / 24;
  const int b = bt >> 11, t = bt & (T_SEQ - 1);
  int off;
  if (hh < 16) off = hh * 128;
  else if (hh < 20) off = 2048 + (hh - 16) * 128;
  else off = 2560 + (hh - 20) * 128;
  const ushort2 xr = *(const ushort2*)(QKV + (size_t)bt * 3072 + off + lane * 2);
  const float xx = __bfloat162float(*(const bf16*)&xr.x);
  const float xy = __bfloat162float(*(const bf16*)&xr.y);
  if (hh < 20) {
    float ss = xx * xx + xy * xy;
    ss += __shfl_xor(ss, 1);  ss += __shfl_xor(ss, 2);  ss += __shfl_xor(ss, 4);
    ss += __shfl_xor(ss, 8);  ss += __shfl_xor(ss, 16); ss += __shfl_xor(ss, 32);
    const float rms = rsqrtf(ss * (1.0f / 128.0f) + 1e-5f);
    const float* w = (hh < 16) ? qw : kw;
    const float x0 = xx * rms * w[lane * 2];
    const float x1 = xy * rms * w[lane * 2 + 1];
    const float inv = exp2f((float)lane * (-13.287712379549449f / 64.0f));
    const float th = (float)t * inv;
    const float sn = sinf(th), cs = cosf(th);
    const float y0 = x0 * cs - x1 * sn;
    const float y1 = x0 * sn + x1 * cs;
    const bf16 o0 = __float2bfloat16(y0), o1 = __float2bfloat16(y1);
    if (hh < 16) {
      bf16* d = Qo + ((size_t)(b * NHEAD + hh) * T_SEQ + t) * HD + lane * 2;
      d[0] = o0; d[1] = o1;
    } else {
      bf16* d = Ko + ((size_t)(b * NKV + (hh - 16)) * T_SEQ + t) * HD + lane * 2;
      d[0] = o0; d[1] = o1;
    }
  } else {
    bf16* d = Vto + ((size_t)(b * NKV + (hh - 20)) * HD + lane * 2) * T_SEQ + t;
    d[0] = __float2bfloat16(xx);
    d[T_SEQ] = __float2bfloat16(xy);
  }
}

// ---------------- GQA causal flash attention: R6 inner loop + flash-split ----------
__constant__ unsigned short JT[30] = {
    0x0605, 0x160A, 0x160B, 0x266B, 0x160F,                          // len 6
    0x0504, 0x1508, 0x1509, 0x2559, 0x256A, 0x150C, 0x150D, 0x255D,  // len 5
    0x150E, 0x255E, 0x35AE, 0x256F, 0x35BF,                          // len 5
    0x0403, 0x1406, 0x1407, 0x2447, 0x2458, 0x245C, 0x349C, 0x34AD,  // len 4
    0x0302, 0x2346,                                                  // len 3
    0x0201, 0x0100};                                                 // len 2,1

#define ATTN_CL 0.12754125f  // (1/sqrt(128)) * log2(e)

__global__ void __launch_bounds__(256, 2) attn_fwd(const bf16* __restrict__ Q,
                                                   const bf16* __restrict__ K,
                                                   const bf16* __restrict__ Vt,
                                                   bf16* __restrict__ Y,
                                                   bf16* __restrict__ PO,
                                                   float* __restrict__ PML) {
  __shared__ bf16 smK[128 * 128];
  __shared__ bf16 smV[128 * 128];

  const int bid = blockIdx.x;
  const int bh = bid & 31;
  const int jobi = bid >> 5;       // 0..29, LPT order
  const unsigned int e = JT[jobi];
  const int jq = e & 15;
  const int lo = (e >> 4) & 15;
  const int len = (e >> 8) & 15;
  const int part = e >> 12;
  const int hi_t = lo + len;

  const int h = bh & (NHEAD - 1), b = bh >> 4;
  const int bkv = b * NKV + (h >> 2);

  const int tid = threadIdx.x, wid = tid >> 6, lane = tid & 63;
  const int l31 = lane & 31, hi = lane >> 5;
  const int q0w = jq * 128 + wid * 32;
  const int trow = tid >> 4, tslot = tid & 15;

  const bf16* Kb = K + (size_t)bkv * T_SEQ * HD;
  const bf16* Vb = Vt + (size_t)bkv * HD * T_SEQ;

  const bf16* Qrow = Q + ((size_t)bh * T_SEQ + q0w + l31) * HD + hi * 8;
  short8 qf[8];
#pragma unroll
  for (int ds = 0; ds < 8; ds++) qf[ds] = *(const short8*)(Qrow + ds * 16);

  f32x16 o[4];
#pragma unroll
  for (int d = 0; d < 4; d++) o[d] = (f32x16)(0.f);
  float mrun = -INFINITY, lrun = 0.f;

  constexpr float CL = ATTN_CL;

  for (int t = lo; t < hi_t; t++) {
    const int k0 = t * 128;
    __syncthreads();
#pragma unroll
    for (int i = 0; i < 8; i++) {
      const int row = i * 16 + trow;
      const int ss = (tslot ^ (row & 15)) * 8;
      gl_lds16(Kb + (size_t)(k0 + row) * HD + ss, (void*)((char*)smK + i * 4096 + wid * 1024));
      gl_lds16(Vb + (size_t)row * T_SEQ + k0 + ss, (void*)((char*)smV + i * 4096 + wid * 1024));
    }
    __syncthreads();

    const bool diag = (t == jq);
    const int glim = diag ? wid : 3;

    f32x16 sg[4];
#pragma unroll
    for (int g = 0; g < 4; g++) {
      if (g > glim) continue;
      f32x16 acc = (f32x16)(0.f);
#pragma unroll
      for (int ds = 0; ds < 8; ds++) {
        const int row = g * 32 + l31;
        const short8 kf = *(const short8*)(smK + (size_t)row * 128 +
                                           (((ds << 1) | hi) ^ (row & 15)) * 8);
        acc = __builtin_amdgcn_mfma_f32_32x32x16_bf16(kf, qf[ds], acc, 0, 0, 0);
      }
      sg[g] = acc;
    }
    float tmax = -INFINITY;
#pragma unroll
    for (int g = 0; g < 4; g++) {
      if (g > glim) continue;
      if (diag && g == wid) {
#pragma unroll
        for (int r = 0; r < 16; r++) {
          const int kr = (r & 3) + 8 * (r >> 2) + (hi << 2);
          if (kr > l31) sg[g][r] = -INFINITY;
        }
      }
#pragma unroll
      for (int r = 0; r < 16; r++) tmax = fmaxf(tmax, sg[g][r]);
    }
    tmax = fmaxf(tmax, __shfl_xor(tmax, 32));
    const float mnew = fmaxf(mrun, tmax);
    const float f = exp2f((mrun - mnew) * CL);
    mrun = mnew;
    lrun *= f;
#pragma unroll
    for (int d = 0; d < 4; d++)
#pragma unroll
      for (int r = 0; r < 16; r++) o[d][r] *= f;

    float lsum = 0.f;
#pragma unroll
    for (int g = 0; g < 4; g++) {
      if (g > glim) continue;
      float pp[16];
      float s0 = 0.f, s1 = 0.f;
#pragma unroll
      for (int r = 0; r < 16; r++) pp[r] = exp2f((sg[g][r] - mnew) * CL);
#pragma unroll
      for (int r = 0; r < 8; r++) { s0 += pp[2 * r]; s1 += pp[2 * r + 1]; }
      lsum += s0 + s1;

      unsigned int w0 = cvtpk_bf16(pp[0], pp[1]),  w2 = cvtpk_bf16(pp[4], pp[5]);
      unsigned int w1 = cvtpk_bf16(pp[2], pp[3]),  w3 = cvtpk_bf16(pp[6], pp[7]);
      unsigned int w4 = cvtpk_bf16(pp[8], pp[9]),  w6 = cvtpk_bf16(pp[12], pp[13]);
      unsigned int w5 = cvtpk_bf16(pp[10], pp[11]), w7 = cvtpk_bf16(pp[14], pp[15]);
      plswap(w0, w2, hi); plswap(w1, w3, hi);
      plswap(w4, w6, hi); plswap(w5, w7, hi);
      union { unsigned int u[4]; short8 s8; } pa0, pa1;
      pa0.u[0] = w0; pa0.u[1] = w1; pa0.u[2] = w2; pa0.u[3] = w3;
      pa1.u[0] = w4; pa1.u[1] = w5; pa1.u[2] = w6; pa1.u[3] = w7;

#pragma unroll
      for (int d = 0; d < 4; d++) {
        const int row = d * 32 + l31;
        const int ks0 = g * 2, ks1 = g * 2 + 1;
        const short8 vf0 = *(const short8*)(smV + (size_t)row * 128 +
                                            (((ks0 << 1) | hi) ^ (row & 15)) * 8);
        const short8 vf1 = *(const short8*)(smV + (size_t)row * 128 +
                                            (((ks1 << 1) | hi) ^ (row & 15)) * 8);
        o[d] = __builtin_amdgcn_mfma_f32_32x32x16_bf16(vf0, pa0.s8, o[d], 0, 0, 0);
        o[d] = __builtin_amdgcn_mfma_f32_32x32x16_bf16(vf1, pa1.s8, o[d], 0, 0, 0);
      }
    }
    lrun += lsum + __shfl_xor(lsum, 32);
  }

  if (part == 0) {
    const float inv = 1.0f / lrun;
    bf16* yrow = Y + ((size_t)(b * T_SEQ + q0w + l31)) * CE + h * HD;
#pragma unroll
    for (int d = 0; d < 4; d++) {
#pragma unroll
      for (int rg = 0; rg < 4; rg++) {
        ushort4 u;
        bf16 e0 = __float2bfloat16(o[d][rg * 4 + 0] * inv);
        bf16 e1 = __float2bfloat16(o[d][rg * 4 + 1] * inv);
        bf16 e2 = __float2bfloat16(o[d][rg * 4 + 2] * inv);
        bf16 e3 = __float2bfloat16(o[d][rg * 4 + 3] * inv);
        u.x = *(const unsigned short*)&e0; u.y = *(const unsigned short*)&e1;
        u.z = *(const unsigned short*)&e2; u.w = *(const unsigned short*)&e3;
        *(ushort4*)(yrow + d * 32 + rg * 8 + (hi << 2)) = u;
      }
    }
  } else {
    const int plocal = (jq < 12) ? (jq - 6) * 2 + (part - 1)
                                 : 12 + (jq - 12) * 3 + (part - 1);
    const int pidx = bh * 24 + plocal;
    bf16* po = PO + (size_t)pidx * 16384;
    const int row = wid * 32 + l31;
#pragma unroll
    for (int d = 0; d < 4; d++) {
#pragma unroll
      for (int rg = 0; rg < 4; rg++) {
        ushort4 u;
        bf16 e0 = __float2bfloat16(o[d][rg * 4 + 0]);
        bf16 e1 = __float2bfloat16(o[d][rg * 4 + 1]);
        bf16 e2 = __float2bfloat16(o[d][rg * 4 + 2]);
        bf16 e3 = __float2bfloat16(o[d][rg * 4 + 3]);
        u.x = *(const unsigned short*)&e0; u.y = *(const unsigned short*)&e1;
        u.z = *(const unsigned short*)&e2; u.w = *(const unsigned short*)&e3;
        *(ushort4*)(po + (size_t)row * 128 + d * 32 + rg * 8 + (hi << 2)) = u;
      }
    }
    if (hi == 0) {
      PML[(size_t)pidx * 256 + row * 2 + 0] = mrun;
      PML[(size_t)pidx * 256 + row * 2 + 1] = lrun;
    }
  }
}

// ---------------- combine split-KV partials (2 or 3 parts) -> final bf16 y ----------
__global__ void __launch_bounds__(256) attn_combine(const bf16* __restrict__ PO,
                                                    const float* __restrict__ PML,
                                                    bf16* __restrict__ Y) {
  const int bid = blockIdx.x;              // 32 bh x 10 J x 4 row-chunks = 1280
  const int rb = bid & 3;
  const int Jl = (bid >> 2) % 10;
  const int bh = bid / 40;
  const int J = 6 + Jl;
  const bool has2 = (J >= 12);
  const int base = bh * 24 + (has2 ? 12 + (J - 12) * 3 : (J - 6) * 2);
  const int tid = threadIdx.x;
  const int row = rb * 32 + (tid >> 3);
  const int c0 = (tid & 7) * 16;
  const int b = bh >> 4, h = bh & 15;

  const float m0 = PML[(size_t)(base + 0) * 256 + row * 2 + 0];
  const float l0 = PML[(size_t)(base + 0) * 256 + row * 2 + 1];
  const float m1 = PML[(size_t)(base + 1) * 256 + row * 2 + 0];
  const float l1 = PML[(size_t)(base + 1) * 256 + row * 2 + 1];
  float m2 = -INFINITY, l2 = 0.f;
  if (has2) {
    m2 = PML[(size_t)(base + 2) * 256 + row * 2 + 0];
    l2 = PML[(size_t)(base + 2) * 256 + row * 2 + 1];
  }
  const float mx = fmaxf(fmaxf(m0, m1), m2);
  const float w0 = exp2f((m0 - mx) * ATTN_CL);
  const float w1 = exp2f((m1 - mx) * ATTN_CL);
  const float w2 = has2 ? exp2f((m2 - mx) * ATTN_CL) : 0.f;
  const float inv = 1.0f / (w0 * l0 + w1 * l1 + w2 * l2);

  const bf16* p0 = PO + (size_t)(base + 0) * 16384 + (size_t)row * 128 + c0;
  const bf16* p1 = PO + (size_t)(base + 1) * 16384 + (size_t)row * 128 + c0;
  const bf16* p2 = PO + (size_t)(base + 2) * 16384 + (size_t)row * 128 + c0;

  float acc[16];
#pragma unroll
  for (int half = 0; half < 2; half++) {
    const short8 v0 = *(const short8*)(p0 + half * 8);
    const short8 v1 = *(const short8*)(p1 + half * 8);
#pragma unroll
    for (int i = 0; i < 8; i++) {
      const unsigned short u0 = (unsigned short)v0[i], u1 = (unsigned short)v1[i];
      acc[half * 8 + i] = w0 * __bfloat162float(*(const bf16*)&u0) +
                          w1 * __bfloat162float(*(const bf16*)&u1);
    }
  }
  if (has2) {
#pragma unroll
    for (int half = 0; half < 2; half++) {
      const short8 v2 = *(const short8*)(p2 + half * 8);
#pragma unroll
      for (int i = 0; i < 8; i++) {
        const unsigned short u2 = (unsigned short)v2[i];
        acc[half * 8 + i] += w2 * __bfloat162float(*(const bf16*)&u2);
      }
    }
  }

  bf16* yp = Y + ((size_t)(b * T_SEQ + J * 128 + row)) * CE + h * HD + c0;
#pragma unroll
  for (int half = 0; half < 2; half++) {
    short8 out;
#pragma unroll
    for (int i = 0; i < 8; i++) {
      const bf16 ev = __float2bfloat16(acc[half * 8 + i] * inv);
      out[i] = *(const short*)&ev;
    }
    *(short8*)(yp + half * 8) = out;
  }
}

// ---------------- launch ----------------
extern "C" void kernel_launch(void* const* d_in, const int* in_sizes, int n_in,
                              void* d_out, int out_size, void* d_ws, size_t ws_size,
                              hipStream_t stream) {
  const float* x   = (const float*)d_in[0];
  const float* wq  = (const float*)d_in[1];
  const float* wk  = (const float*)d_in[2];
  const float* wv  = (const float*)d_in[3];
  const float* wc  = (const float*)d_in[4];
  const float* qnw = (const float*)d_in[5];
  const float* knw = (const float*)d_in[6];
  float* out = (float*)d_out;

  char* ws = (char*)d_ws;
  bf16*  xb    = (bf16*)(ws);                    // 16 MB
  bf16*  wqkvt = (bf16*)(ws + 16777216);         // 12 MB
  bf16*  wct   = (bf16*)(ws + 29360128);         //  8 MB
  bf16*  qkv   = (bf16*)(ws + 37748736);         // 24 MB (dead after qkv_post)
  bf16*  partO = (bf16*)(ws + 37748736);         // 24 MB (overlaps dead qkv)
  float* partML= (float*)(ws + 62914560);        // 768 KB
  bf16*  Qb    = (bf16*)(ws + 88080384);         // 16 MB (B,H,T,D)
  bf16*  Kb    = (bf16*)(ws + 104857600);        //  4 MB (B,KVH,T,D)
  bf16*  Vtb   = (bf16*)(ws + 109051904);        //  4 MB (B,KVH,D,T)
  bf16*  yb    = (bf16*)(ws + 113246208);        // 16 MB

  prep<<<18432, 256, 0, stream>>>(x, wq, wk, wv, wc, xb, wqkvt, wct);
  gemm8i<256, 256, 2, 4, true><<<192, 512, 0, stream>>>(xb, wqkvt, qkv, 4096, 3072, 2048);
  qkv_post<<<24576, 256, 0, stream>>>(qkv, qnw, knw, Qb, Kb, Vtb);
  attn_fwd<<<960, 256, 0, stream>>>(Qb, Kb, Vtb, yb, partO, partML);
  attn_combine<<<1280, 256, 0, stream>>>(partO, partML, yb);
  gemm8i<128, 256, 2, 4, false><<<256, 512, 0, stream>>>(yb, wct, out, 4096, 2048, 2048);
}

// Round 16
// 217.628 us; speedup vs baseline: 1.0460x; 1.0260x over previous
//
#include <hip/hip_runtime.h>
#include <hip/hip_bf16.h>
#include <cstdint>
#include <cstddef>

using bf16 = __hip_bfloat16;
typedef __attribute__((ext_vector_type(8))) short short8;
typedef __attribute__((ext_vector_type(4))) float f32x4;
typedef __attribute__((ext_vector_type(16))) float f32x16;

#define T_SEQ 2048
#define NHEAD 16
#define NKV 4
#define HD 128
#define CE 2048

__device__ __forceinline__ void gl_lds16(const void* g, void* l) {
  __builtin_amdgcn_global_load_lds(
      (const __attribute__((address_space(1))) unsigned int*)g,
      (__attribute__((address_space(3))) unsigned int*)l, 16, 0, 0);
}

__device__ __forceinline__ unsigned int cvtpk_bf16(float lo, float hi) {
  unsigned int r;
  asm("v_cvt_pk_bf16_f32 %0, %1, %2" : "=v"(r) : "v"(lo), "v"(hi));
  return r;
}

__device__ __forceinline__ void plswap(unsigned int& x, unsigned int& y, int hi) {
#if __has_builtin(__builtin_amdgcn_permlane32_swap)
  auto r = __builtin_amdgcn_permlane32_swap(x, y, false, false);
  x = r[0];
  y = r[1];
#else
  unsigned int xp = (unsigned int)__shfl_xor((int)x, 32);
  unsigned int yp = (unsigned int)__shfl_xor((int)y, 32);
  unsigned int nx = hi ? yp : x;
  unsigned int ny = hi ? y : xp;
  x = nx;
  y = ny;
#endif
}

// ---------------- fused prep: x->bf16 (blocks 0..8191) + 4 weight transposes ----------
__global__ void __launch_bounds__(256) prep(const float* __restrict__ x,
                                            const float* __restrict__ wq,
                                            const float* __restrict__ wk,
                                            const float* __restrict__ wv,
                                            const float* __restrict__ wc,
                                            bf16* __restrict__ xb,
                                            bf16* __restrict__ wqkvt,
                                            bf16* __restrict__ wct) {
  __shared__ float tile[32][33];
  const int tid = threadIdx.x;
  int bb = blockIdx.x;
  if (bb < 8192) {
    const int i = bb * 256 + tid;
    const float4 v = ((const float4*)x)[i];
    bf16 b0 = __float2bfloat16(v.x), b1 = __float2bfloat16(v.y),
         b2 = __float2bfloat16(v.z), b3 = __float2bfloat16(v.w);
    ushort4 u;
    u.x = *(const unsigned short*)&b0; u.y = *(const unsigned short*)&b1;
    u.z = *(const unsigned short*)&b2; u.w = *(const unsigned short*)&b3;
    ((ushort4*)xb)[i] = u;
    return;
  }
  bb -= 8192;
  const float* W;
  bf16* Wt;
  int N, bx, by;
  if (bb < 4096) {
    W = wq; Wt = wqkvt; N = 2048; bx = bb & 63; by = bb >> 6;
  } else if (bb < 5120) {
    const int c = bb - 4096;
    W = wk; Wt = wqkvt + (size_t)2048 * 2048; N = 512; bx = c & 15; by = c >> 4;
  } else if (bb < 6144) {
    const int c = bb - 5120;
    W = wv; Wt = wqkvt + (size_t)2560 * 2048; N = 512; bx = c & 15; by = c >> 4;
  } else {
    const int c = bb - 6144;
    W = wc; Wt = wct; N = 2048; bx = c & 63; by = c >> 6;
  }
  const int tx = tid & 31, ty = tid >> 5;  // 32 x 8
#pragma unroll
  for (int i = 0; i < 4; i++) {
    const int r = by * 32 + ty + i * 8;
    tile[ty + i * 8][tx] = W[(size_t)r * N + bx * 32 + tx];
  }
  __syncthreads();
#pragma unroll
  for (int i = 0; i < 4; i++) {
    const int n = bx * 32 + ty + i * 8;
    Wt[(size_t)n * 2048 + by * 32 + tx] = __float2bfloat16(tile[tx][ty + i * 8]);
  }
}

// ---------------- m201-derived 8-phase/2-K-tile GEMM (XCD swizzle restored) ----------
template <int BM, int BN, int WM, int WN, bool OBF>
__global__ void __launch_bounds__(512, 2)
gemm8i(const bf16* __restrict__ A, const bf16* __restrict__ Bt,
       void* __restrict__ Cv, int M, int N, int K) {
  constexpr int AWS = BM / 2 / WM;
  constexpr int BWS = BN / 2 / WN;
  constexpr int MH = AWS / 16;
  constexpr int NH = BWS / 16;
  constexpr int AH = BM / 128;
  constexpr int BH = BN / 128;
  constexpr int G = 2 * AH + BH;
  __shared__ bf16 smA[2][BM * 64];
  __shared__ bf16 smB[2][BN * 64];

  const int tid = threadIdx.x, lane = tid & 63, wid = tid >> 6;
  const int l15 = lane & 15, l4 = lane >> 4;
  const int wr = wid / WN, wc = wid % WN;

  // bijective XCD-aware block swizzle (m204): L2 locality worth ~25% FETCH (R15 A/B)
  const int nwg = gridDim.x;
  const int q = nwg >> 3, r = nwg & 7;
  const int xcd = blockIdx.x & 7, lin = blockIdx.x >> 3;
  const int wg = (xcd < r ? xcd * (q + 1) : r * (q + 1) + (xcd - r) * q) + lin;
  const int gw = N / BN;
  const int by = wg / gw, bx = wg % gw;
  const int row0 = by * BM, col0 = bx * BN;
  const int NT = K >> 6;
  const int NI = NT >> 1;

  const bf16* Ag = A + (size_t)row0 * K;
  const bf16* Bg = Bt + (size_t)col0 * K;

  auto stA = [&](int t, int h, int pb) {
    const int k0 = t << 6;
#pragma unroll
    for (int j = 0; j < AH; j++) {
      const int c = (h * AH + j) * 512 + tid;
      const int rowi = c >> 3;
      gl_lds16(Ag + (size_t)rowi * K + k0 + (((c & 7) ^ (rowi & 7)) << 3),
               (void*)(&smA[pb][(size_t)c << 3]));
    }
  };
  auto stB = [&](int t, int h, int pb) {
    const int k0 = t << 6;
#pragma unroll
    for (int j = 0; j < BH; j++) {
      const int c = (h * BH + j) * 512 + tid;
      const int rowi = c >> 3;
      gl_lds16(Bg + (size_t)rowi * K + k0 + (((c & 7) ^ (rowi & 7)) << 3),
               (void*)(&smB[pb][(size_t)c << 3]));
    }
  };
  auto rdA = [&](const bf16* sA, int mh, short8 (&dst)[MH][2]) {
#pragma unroll
    for (int i = 0; i < MH; i++) {
      const int rowl = mh * (BM / 2) + wr * AWS + i * 16 + l15;
#pragma unroll
      for (int kk = 0; kk < 2; kk++)
        dst[i][kk] = *(const short8*)(sA + rowl * 64 +
                                      ((((kk << 2) | l4) ^ (rowl & 7)) << 3));
    }
  };
  auto rdB = [&](const bf16* sB, int nh, short8 (&dst)[NH][2]) {
#pragma unroll
    for (int j = 0; j < NH; j++) {
      const int rowl = nh * (BN / 2) + wc * BWS + j * 16 + l15;
#pragma unroll
      for (int kk = 0; kk < 2; kk++)
        dst[j][kk] = *(const short8*)(sB + rowl * 64 +
                                      ((((kk << 2) | l4) ^ (rowl & 7)) << 3));
    }
  };

  f32x4 acc[2][2][MH][NH];
#pragma unroll
  for (int mh = 0; mh < 2; mh++)
#pragma unroll
    for (int nh = 0; nh < 2; nh++)
#pragma unroll
      for (int i = 0; i < MH; i++)
#pragma unroll
        for (int j = 0; j < NH; j++) acc[mh][nh][i][j] = (f32x4){0.f, 0.f, 0.f, 0.f};

  auto mmq = [&](short8 (&a)[MH][2], short8 (&b)[NH][2], f32x4 (&ac)[MH][NH]) {
    __builtin_amdgcn_s_setprio(1);
#pragma unroll
    for (int i = 0; i < MH; i++)
#pragma unroll
      for (int j = 0; j < NH; j++)
#pragma unroll
        for (int kk = 0; kk < 2; kk++)
          ac[i][j] = __builtin_amdgcn_mfma_f32_16x16x32_bf16(a[i][kk], b[j][kk],
                                                             ac[i][j], 0, 0, 0);
    __builtin_amdgcn_s_setprio(0);
  };

  short8 a0[MH][2], a1[MH][2], b0[NH][2], b1[NH][2];

#define LGKM0_SB                                            \
  asm volatile("s_waitcnt lgkmcnt(0)" ::: "memory");        \
  __builtin_amdgcn_sched_barrier(0);
#define GATE_G                                              \
  asm volatile("s_waitcnt vmcnt(%0)" ::"i"(G) : "memory");

  stA(0, 0, 0); stB(0, 0, 0); stA(0, 1, 0); stB(0, 1, 0);
  stA(1, 0, 1); stB(1, 0, 1); stA(1, 1, 1);
  GATE_G
  __builtin_amdgcn_s_barrier();

  for (int i = 0; i < NI - 1; ++i) {
    const int u = 2 * i, v = u + 1;
    stB(v, 1, 1);
    rdA(smA[0], 0, a0); rdB(smB[0], 0, b0);
    __builtin_amdgcn_s_barrier();
    LGKM0_SB
    mmq(a0, b0, acc[0][0]);
    __builtin_amdgcn_s_barrier();
    stA(u + 2, 0, 0);
    rdA(smA[0], 1, a1);
    __builtin_amdgcn_s_barrier();
    LGKM0_SB
    mmq(a1, b0, acc[1][0]);
    __builtin_amdgcn_s_barrier();
    stB(u + 2, 0, 0);
    rdB(smB[0], 1, b1);
    __builtin_amdgcn_s_barrier();
    LGKM0_SB
    mmq(a1, b1, acc[1][1]);
    __builtin_amdgcn_s_barrier();
    stA(u + 2, 1, 0);
    mmq(a0, b1, acc[0][1]);
    GATE_G
    __builtin_amdgcn_s_barrier();
    stB(u + 2, 1, 0);
    rdA(smA[1], 0, a0); rdB(smB[1], 0, b0);
    __builtin_amdgcn_s_barrier();
    LGKM0_SB
    mmq(a0, b0, acc[0][0]);
    __builtin_amdgcn_s_barrier();
    stA(v + 2, 0, 1);
    rdA(smA[1], 1, a1);
    __builtin_amdgcn_s_barrier();
    LGKM0_SB
    mmq(a1, b0, acc[1][0]);
    __builtin_amdgcn_s_barrier();
    stB(v + 2, 0, 1);
    rdB(smB[1], 1, b1);
    __builtin_amdgcn_s_barrier();
    LGKM0_SB
    mmq(a1, b1, acc[1][1]);
    __builtin_amdgcn_s_barrier();
    stA(v + 2, 1, 1);
    mmq(a0, b1, acc[0][1]);
    GATE_G
    __builtin_amdgcn_s_barrier();
  }

  {
    stB(NT - 1, 1, 1);
    rdA(smA[0], 0, a0); rdB(smB[0], 0, b0);
    __builtin_amdgcn_s_barrier();
    LGKM0_SB
    mmq(a0, b0, acc[0][0]);
    __builtin_amdgcn_s_barrier();
    rdA(smA[0], 1, a1);
    __builtin_amdgcn_s_barrier();
    LGKM0_SB
    mmq(a1, b0, acc[1][0]);
    __builtin_amdgcn_s_barrier();
    rdB(smB[0], 1, b1);
    __builtin_amdgcn_s_barrier();
    LGKM0_SB
    mmq(a1, b1, acc[1][1]);
    __builtin_amdgcn_s_barrier();
    mmq(a0, b1, acc[0][1]);
    asm volatile("s_waitcnt vmcnt(0)" ::: "memory");
    __builtin_amdgcn_s_barrier();
    rdA(smA[1], 0, a0); rdB(smB[1], 0, b0);
    __builtin_amdgcn_s_barrier();
    LGKM0_SB
    mmq(a0, b0, acc[0][0]);
    __builtin_amdgcn_s_barrier();
    rdA(smA[1], 1, a1);
    __builtin_amdgcn_s_barrier();
    LGKM0_SB
    mmq(a1, b0, acc[1][0]);
    __builtin_amdgcn_s_barrier();
    rdB(smB[1], 1, b1);
    __builtin_amdgcn_s_barrier();
    LGKM0_SB
    mmq(a1, b1, acc[1][1]);
    mmq(a0, b1, acc[0][1]);
  }

#pragma unroll
  for (int mh = 0; mh < 2; mh++)
#pragma unroll
    for (int nh = 0; nh < 2; nh++)
#pragma unroll
      for (int i = 0; i < MH; i++)
#pragma unroll
        for (int j = 0; j < NH; j++)
#pragma unroll
          for (int rr = 0; rr < 4; rr++) {
            const size_t row = row0 + mh * (BM / 2) + wr * AWS + i * 16 + l4 * 4 + rr;
            const size_t col = col0 + nh * (BN / 2) + wc * BWS + j * 16 + l15;
            if constexpr (OBF)
              ((bf16*)Cv)[row * N + col] = __float2bfloat16(acc[mh][nh][i][j][rr]);
            else
              ((float*)Cv)[row * N + col] = acc[mh][nh][i][j][rr];
          }
#undef LGKM0_SB
#undef GATE_G
}

// ---------------- RMSNorm + RoPE + layout (bf16 input) ----------------
__global__ void __launch_bounds__(256) qkv_post(const bf16* __restrict__ QKV,
                                                const float* __restrict__ qw,
                                                const float* __restrict__ kw,
                                                bf16* __restrict__ Qo,
                                                bf16* __restrict__ Ko,
                                                bf16* __restrict__ Vto) {
  const int g = blockIdx.x * 4 + (threadIdx.x >> 6);
  const int lane = threadIdx.x & 63;
  const int hh = g % 24;
  const int bt = g / 24;
  const int b = bt >> 11, t = bt & (T_SEQ - 1);
  int off;
  if (hh < 16) off = hh * 128;
  else if (hh < 20) off = 2048 + (hh - 16) * 128;
  else off = 2560 + (hh - 20) * 128;
  const ushort2 xr = *(const ushort2*)(QKV + (size_t)bt * 3072 + off + lane * 2);
  const float xx = __bfloat162float(*(const bf16*)&xr.x);
  const float xy = __bfloat162float(*(const bf16*)&xr.y);
  if (hh < 20) {
    float ss = xx * xx + xy * xy;
    ss += __shfl_xor(ss, 1);  ss += __shfl_xor(ss, 2);  ss += __shfl_xor(ss, 4);
    ss += __shfl_xor(ss, 8);  ss += __shfl_xor(ss, 16); ss += __shfl_xor(ss, 32);
    const float rms = rsqrtf(ss * (1.0f / 128.0f) + 1e-5f);
    const float* w = (hh < 16) ? qw : kw;
    const float x0 = xx * rms * w[lane * 2];
    const float x1 = xy * rms * w[lane * 2 + 1];
    const float inv = exp2f((float)lane * (-13.287712379549449f / 64.0f));
    const float th = (float)t * inv;
    const float sn = sinf(th), cs = cosf(th);
    const float y0 = x0 * cs - x1 * sn;
    const float y1 = x0 * sn + x1 * cs;
    const bf16 o0 = __float2bfloat16(y0), o1 = __float2bfloat16(y1);
    if (hh < 16) {
      bf16* d = Qo + ((size_t)(b * NHEAD + hh) * T_SEQ + t) * HD + lane * 2;
      d[0] = o0; d[1] = o1;
    } else {
      bf16* d = Ko + ((size_t)(b * NKV + (hh - 16)) * T_SEQ + t) * HD + lane * 2;
      d[0] = o0; d[1] = o1;
    }
  } else {
    bf16* d = Vto + ((size_t)(b * NKV + (hh - 20)) * HD + lane * 2) * T_SEQ + t;
    d[0] = __float2bfloat16(xx);
    d[T_SEQ] = __float2bfloat16(xy);
  }
}

// ---------------- GQA causal flash attention: R6 inner loop + flash-split ----------
__constant__ unsigned short JT[30] = {
    0x0605, 0x160A, 0x160B, 0x266B, 0x160F,                          // len 6
    0x0504, 0x1508, 0x1509, 0x2559, 0x256A, 0x150C, 0x150D, 0x255D,  // len 5
    0x150E, 0x255E, 0x35AE, 0x256F, 0x35BF,                          // len 5
    0x0403, 0x1406, 0x1407, 0x2447, 0x2458, 0x245C, 0x349C, 0x34AD,  // len 4
    0x0302, 0x2346,                                                  // len 3
    0x0201, 0x0100};                                                 // len 2,1

#define ATTN_CL 0.12754125f  // (1/sqrt(128)) * log2(e)

__global__ void __launch_bounds__(256, 2) attn_fwd(const bf16* __restrict__ Q,
                                                   const bf16* __restrict__ K,
                                                   const bf16* __restrict__ Vt,
                                                   bf16* __restrict__ Y,
                                                   bf16* __restrict__ PO,
                                                   float* __restrict__ PML) {
  __shared__ bf16 smK[128 * 128];
  __shared__ bf16 smV[128 * 128];

  const int bid = blockIdx.x;
  const int bh = bid & 31;
  const int jobi = bid >> 5;       // 0..29, LPT order
  const unsigned int e = JT[jobi];
  const int jq = e & 15;
  const int lo = (e >> 4) & 15;
  const int len = (e >> 8) & 15;
  const int part = e >> 12;
  const int hi_t = lo + len;

  const int h = bh & (NHEAD - 1), b = bh >> 4;
  const int bkv = b * NKV + (h >> 2);

  const int tid = threadIdx.x, wid = tid >> 6, lane = tid & 63;
  const int l31 = lane & 31, hi = lane >> 5;
  const int q0w = jq * 128 + wid * 32;
  const int trow = tid >> 4, tslot = tid & 15;

  const bf16* Kb = K + (size_t)bkv * T_SEQ * HD;
  const bf16* Vb = Vt + (size_t)bkv * HD * T_SEQ;

  const bf16* Qrow = Q + ((size_t)bh * T_SEQ + q0w + l31) * HD + hi * 8;
  short8 qf[8];
#pragma unroll
  for (int ds = 0; ds < 8; ds++) qf[ds] = *(const short8*)(Qrow + ds * 16);

  f32x16 o[4];
#pragma unroll
  for (int d = 0; d < 4; d++) o[d] = (f32x16)(0.f);
  float mrun = -INFINITY, lrun = 0.f;

  constexpr float CL = ATTN_CL;

  for (int t = lo; t < hi_t; t++) {
    const int k0 = t * 128;
    __syncthreads();
#pragma unroll
    for (int i = 0; i < 8; i++) {
      const int row = i * 16 + trow;
      const int ss = (tslot ^ (row & 15)) * 8;
      gl_lds16(Kb + (size_t)(k0 + row) * HD + ss, (void*)((char*)smK + i * 4096 + wid * 1024));
      gl_lds16(Vb + (size_t)row * T_SEQ + k0 + ss, (void*)((char*)smV + i * 4096 + wid * 1024));
    }
    __syncthreads();

    const bool diag = (t == jq);
    const int glim = diag ? wid : 3;

    f32x16 sg[4];
#pragma unroll
    for (int g = 0; g < 4; g++) {
      if (g > glim) continue;
      f32x16 acc = (f32x16)(0.f);
#pragma unroll
      for (int ds = 0; ds < 8; ds++) {
        const int row = g * 32 + l31;
        const short8 kf = *(const short8*)(smK + (size_t)row * 128 +
                                           (((ds << 1) | hi) ^ (row & 15)) * 8);
        acc = __builtin_amdgcn_mfma_f32_32x32x16_bf16(kf, qf[ds], acc, 0, 0, 0);
      }
      sg[g] = acc;
    }
    float tmax = -INFINITY;
#pragma unroll
    for (int g = 0; g < 4; g++) {
      if (g > glim) continue;
      if (diag && g == wid) {
#pragma unroll
        for (int r = 0; r < 16; r++) {
          const int kr = (r & 3) + 8 * (r >> 2) + (hi << 2);
          if (kr > l31) sg[g][r] = -INFINITY;
        }
      }
#pragma unroll
      for (int r = 0; r < 16; r++) tmax = fmaxf(tmax, sg[g][r]);
    }
    tmax = fmaxf(tmax, __shfl_xor(tmax, 32));
    const float mnew = fmaxf(mrun, tmax);
    const float f = exp2f((mrun - mnew) * CL);
    mrun = mnew;
    lrun *= f;
#pragma unroll
    for (int d = 0; d < 4; d++)
#pragma unroll
      for (int r = 0; r < 16; r++) o[d][r] *= f;

    float lsum = 0.f;
#pragma unroll
    for (int g = 0; g < 4; g++) {
      if (g > glim) continue;
      float pp[16];
      float s0 = 0.f, s1 = 0.f;
#pragma unroll
      for (int r = 0; r < 16; r++) pp[r] = exp2f((sg[g][r] - mnew) * CL);
#pragma unroll
      for (int r = 0; r < 8; r++) { s0 += pp[2 * r]; s1 += pp[2 * r + 1]; }
      lsum += s0 + s1;

      unsigned int w0 = cvtpk_bf16(pp[0], pp[1]),  w2 = cvtpk_bf16(pp[4], pp[5]);
      unsigned int w1 = cvtpk_bf16(pp[2], pp[3]),  w3 = cvtpk_bf16(pp[6], pp[7]);
      unsigned int w4 = cvtpk_bf16(pp[8], pp[9]),  w6 = cvtpk_bf16(pp[12], pp[13]);
      unsigned int w5 = cvtpk_bf16(pp[10], pp[11]), w7 = cvtpk_bf16(pp[14], pp[15]);
      plswap(w0, w2, hi); plswap(w1, w3, hi);
      plswap(w4, w6, hi); plswap(w5, w7, hi);
      union { unsigned int u[4]; short8 s8; } pa0, pa1;
      pa0.u[0] = w0; pa0.u[1] = w1; pa0.u[2] = w2; pa0.u[3] = w3;
      pa1.u[0] = w4; pa1.u[1] = w5; pa1.u[2] = w6; pa1.u[3] = w7;

#pragma unroll
      for (int d = 0; d < 4; d++) {
        const int row = d * 32 + l31;
        const int ks0 = g * 2, ks1 = g * 2 + 1;
        const short8 vf0 = *(const short8*)(smV + (size_t)row * 128 +
                                            (((ks0 << 1) | hi) ^ (row & 15)) * 8);
        const short8 vf1 = *(const short8*)(smV + (size_t)row * 128 +
                                            (((ks1 << 1) | hi) ^ (row & 15)) * 8);
        o[d] = __builtin_amdgcn_mfma_f32_32x32x16_bf16(vf0, pa0.s8, o[d], 0, 0, 0);
        o[d] = __builtin_amdgcn_mfma_f32_32x32x16_bf16(vf1, pa1.s8, o[d], 0, 0, 0);
      }
    }
    lrun += lsum + __shfl_xor(lsum, 32);
  }

  if (part == 0) {
    const float inv = 1.0f / lrun;
    bf16* yrow = Y + ((size_t)(b * T_SEQ + q0w + l31)) * CE + h * HD;
#pragma unroll
    for (int d = 0; d < 4; d++) {
#pragma unroll
      for (int rg = 0; rg < 4; rg++) {
        ushort4 u;
        bf16 e0 = __float2bfloat16(o[d][rg * 4 + 0] * inv);
        bf16 e1 = __float2bfloat16(o[d][rg * 4 + 1] * inv);
        bf16 e2 = __float2bfloat16(o[d][rg * 4 + 2] * inv);
        bf16 e3 = __float2bfloat16(o[d][rg * 4 + 3] * inv);
        u.x = *(const unsigned short*)&e0; u.y = *(const unsigned short*)&e1;
        u.z = *(const unsigned short*)&e2; u.w = *(const unsigned short*)&e3;
        *(ushort4*)(yrow + d * 32 + rg * 8 + (hi << 2)) = u;
      }
    }
  } else {
    const int plocal = (jq < 12) ? (jq - 6) * 2 + (part - 1)
                                 : 12 + (jq - 12) * 3 + (part - 1);
    const int pidx = bh * 24 + plocal;
    bf16* po = PO + (size_t)pidx * 16384;
    const int row = wid * 32 + l31;
#pragma unroll
    for (int d = 0; d < 4; d++) {
#pragma unroll
      for (int rg = 0; rg < 4; rg++) {
        ushort4 u;
        bf16 e0 = __float2bfloat16(o[d][rg * 4 + 0]);
        bf16 e1 = __float2bfloat16(o[d][rg * 4 + 1]);
        bf16 e2 = __float2bfloat16(o[d][rg * 4 + 2]);
        bf16 e3 = __float2bfloat16(o[d][rg * 4 + 3]);
        u.x = *(const unsigned short*)&e0; u.y = *(const unsigned short*)&e1;
        u.z = *(const unsigned short*)&e2; u.w = *(const unsigned short*)&e3;
        *(ushort4*)(po + (size_t)row * 128 + d * 32 + rg * 8 + (hi << 2)) = u;
      }
    }
    if (hi == 0) {
      PML[(size_t)pidx * 256 + row * 2 + 0] = mrun;
      PML[(size_t)pidx * 256 + row * 2 + 1] = lrun;
    }
  }
}

// ---------------- combine split-KV partials (2 or 3 parts) -> final bf16 y ----------
__global__ void __launch_bounds__(256) attn_combine(const bf16* __restrict__ PO,
                                                    const float* __restrict__ PML,
                                                    bf16* __restrict__ Y) {
  const int bid = blockIdx.x;              // 32 bh x 10 J x 4 row-chunks = 1280
  const int rb = bid & 3;
  const int Jl = (bid >> 2) % 10;
  const int bh = bid / 40;
  const int J = 6 + Jl;
  const bool has2 = (J >= 12);
  const int base = bh * 24 + (has2 ? 12 + (J - 12) * 3 : (J - 6) * 2);
  const int tid = threadIdx.x;
  const int row = rb * 32 + (tid >> 3);
  const int c0 = (tid & 7) * 16;
  const int b = bh >> 4, h = bh & 15;

  const float m0 = PML[(size_t)(base + 0) * 256 + row * 2 + 0];
  const float l0 = PML[(size_t)(base + 0) * 256 + row * 2 + 1];
  const float m1 = PML[(size_t)(base + 1) * 256 + row * 2 + 0];
  const float l1 = PML[(size_t)(base + 1) * 256 + row * 2 + 1];
  float m2 = -INFINITY, l2 = 0.f;
  if (has2) {
    m2 = PML[(size_t)(base + 2) * 256 + row * 2 + 0];
    l2 = PML[(size_t)(base + 2) * 256 + row * 2 + 1];
  }
  const float mx = fmaxf(fmaxf(m0, m1), m2);
  const float w0 = exp2f((m0 - mx) * ATTN_CL);
  const float w1 = exp2f((m1 - mx) * ATTN_CL);
  const float w2 = has2 ? exp2f((m2 - mx) * ATTN_CL) : 0.f;
  const float inv = 1.0f / (w0 * l0 + w1 * l1 + w2 * l2);

  const bf16* p0 = PO + (size_t)(base + 0) * 16384 + (size_t)row * 128 + c0;
  const bf16* p1 = PO + (size_t)(base + 1) * 16384 + (size_t)row * 128 + c0;
  const bf16* p2 = PO + (size_t)(base + 2) * 16384 + (size_t)row * 128 + c0;

  float acc[16];
#pragma unroll
  for (int half = 0; half < 2; half++) {
    const short8 v0 = *(const short8*)(p0 + half * 8);
    const short8 v1 = *(const short8*)(p1 + half * 8);
#pragma unroll
    for (int i = 0; i < 8; i++) {
      const unsigned short u0 = (unsigned short)v0[i], u1 = (unsigned short)v1[i];
      acc[half * 8 + i] = w0 * __bfloat162float(*(const bf16*)&u0) +
                          w1 * __bfloat162float(*(const bf16*)&u1);
    }
  }
  if (has2) {
#pragma unroll
    for (int half = 0; half < 2; half++) {
      const short8 v2 = *(const short8*)(p2 + half * 8);
#pragma unroll
      for (int i = 0; i < 8; i++) {
        const unsigned short u2 = (unsigned short)v2[i];
        acc[half * 8 + i] += w2 * __bfloat162float(*(const bf16*)&u2);
      }
    }
  }

  bf16* yp = Y + ((size_t)(b * T_SEQ + J * 128 + row)) * CE + h * HD + c0;
#pragma unroll
  for (int half = 0; half < 2; half++) {
    short8 out;
#pragma unroll
    for (int i = 0; i < 8; i++) {
      const bf16 ev = __float2bfloat16(acc[half * 8 + i] * inv);
      out[i] = *(const short*)&ev;
    }
    *(short8*)(yp + half * 8) = out;
  }
}

// ---------------- launch ----------------
extern "C" void kernel_launch(void* const* d_in, const int* in_sizes, int n_in,
                              void* d_out, int out_size, void* d_ws, size_t ws_size,
                              hipStream_t stream) {
  const float* x   = (const float*)d_in[0];
  const float* wq  = (const float*)d_in[1];
  const float* wk  = (const float*)d_in[2];
  const float* wv  = (const float*)d_in[3];
  const float* wc  = (const float*)d_in[4];
  const float* qnw = (const float*)d_in[5];
  const float* knw = (const float*)d_in[6];
  float* out = (float*)d_out;

  char* ws = (char*)d_ws;
  bf16*  xb    = (bf16*)(ws);                    // 16 MB
  bf16*  wqkvt = (bf16*)(ws + 16777216);         // 12 MB
  bf16*  wct   = (bf16*)(ws + 29360128);         //  8 MB
  bf16*  qkv   = (bf16*)(ws + 37748736);         // 24 MB (dead after qkv_post)
  bf16*  partO = (bf16*)(ws + 37748736);         // 24 MB (overlaps dead qkv)
  float* partML= (float*)(ws + 62914560);        // 768 KB
  bf16*  Qb    = (bf16*)(ws + 88080384);         // 16 MB (B,H,T,D)
  bf16*  Kb    = (bf16*)(ws + 104857600);        //  4 MB (B,KVH,T,D)
  bf16*  Vtb   = (bf16*)(ws + 109051904);        //  4 MB (B,KVH,D,T)
  bf16*  yb    = (bf16*)(ws + 113246208);        // 16 MB

  prep<<<18432, 256, 0, stream>>>(x, wq, wk, wv, wc, xb, wqkvt, wct);
  gemm8i<256, 256, 2, 4, true><<<192, 512, 0, stream>>>(xb, wqkvt, qkv, 4096, 3072, 2048);
  qkv_post<<<24576, 256, 0, stream>>>(qkv, qnw, knw, Qb, Kb, Vtb);
  attn_fwd<<<960, 256, 0, stream>>>(Qb, Kb, Vtb, yb, partO, partML);
  attn_combine<<<1280, 256, 0, stream>>>(partO, partML, yb);
  gemm8i<128, 256, 2, 4, false><<<256, 512, 0, stream>>>(yb, wct, out, 4096, 2048, 2048);
}